// Round 6
// baseline (145.141 us; speedup 1.0000x reference)
//
#include <hip/hip_runtime.h>
#include <math.h>

// Focal_loss2 — R19: conditional gt loads (miss-count reduction).
// R18 confirmed pos-tail theory (141.2->137.7). Surviving model for the
// remaining fused time: time = miss count / fixed per-CU L1-fill throughput
// (explains R13 NT +26% = more fills; R15/R16/R17 concurrency nulls).
// R19 attacks the NUMERATOR: gt (prob) = 37.8 MB of the unique footprint,
// but gt only GATES accumulation — a quad needs gt only if one of its 4
// outputs passes the 3x3x3 local-max test (~14% of lanes). Compute the max
// test first, load the gt quad ONLY for passing lanes (exec-masked lanes
// fetch nothing) -> ~86% of gt misses removed. Result-identical.
// March/grid = R18: z-paired rolling marcher, (256,4), 512 A (yc=8) +
// 256 B (yc=4, 128 thr), pos block at bid 0 (overlaps march, concurrent
// levels, parallel min-scan), logits PLAIN (NT regressed R13), no global
// atomics (R14), stream-ordered finalize.
// Pre-commit: FETCH halves but time null => miss-count model dead, declare
// roofline next round.
//   neg: w = sigmoid(x)^2 * (gt==-1) * (x is 3x3x3 local max); loss += softplus(x)*w
//        local-max test in logit space (monotone sigmoid; validated R3-R18, absmax 0.0)
//   pos: 64 coords/batch/level gather; w1=(1-sigmoid)^2; per-(b,tag) min of w1
// ws layout (floats): f2[bid] = {loss,wsum} for neg bid in [1,769);
//   [1600..1603] = losspos_a,cntpos_a,losspos_b,cntpos_b
// out: [0]=cls_loss_pos [1]=cls_loss_neg [2]=count_pos [3]=count_neg
//      [4]=wsum_pos [5]=wsum_neg [6..37]=pred_prob_min[2][B=2][T=8]

#define NBLK_A 512    // 4 vol x 8 z-groups(16 z) x 16 y-chunks(8 y)
#define NBLK_B 256    // 4 vol x 4 z-groups(16 z) x 16 y-chunks(4 y)
#define NBLK_NEG (NBLK_A + NBLK_B)
#define NBLK_TOTAL (NBLK_NEG + 1)
#define WS_POS 1600   // clear of f2[0..768] = floats [0..1538)

using f4 = __attribute__((ext_vector_type(4))) float;
using f2 = __attribute__((ext_vector_type(2))) float;

__device__ __forceinline__ float fmax3(float a, float b, float c) {
    return fmaxf(a, fmaxf(b, c));
}

__device__ __forceinline__ f4 fmax3v(f4 a, f4 b, f4 c) {
    f4 r;
    r.x = fmax3(a.x, b.x, c.x); r.y = fmax3(a.y, b.y, c.y);
    r.z = fmax3(a.z, b.z, c.z); r.w = fmax3(a.w, b.w, c.w);
    return r;
}

// Emit one output quad. x-halo via wave shuffle (xq in low lane bits; group
// edges overridden by the clamp rule). gt quad is loaded ONLY if some output
// of this quad passes the local-max test (skip == gt!=-1: identical result).
// All shuffles execute before the divergent early-out (convergence-safe).
template <int XQ>
__device__ __forceinline__ void emit_row_cond(
    const f4 zw0, const f4 zw1, const f4 zw2, const f4 c,
    const float* __restrict__ gquad, int xq, float& loss, float& wsum)
{
    f4 cz = fmax3v(zw0, zw1, zw2);                    // y-fold
    float lco = __shfl_up(cz.w, 1);   if (xq == 0)      lco = cz.x;
    float rco = __shfl_down(cz.x, 1); if (xq == XQ - 1) rco = cz.w;
    float ms[4] = {fmax3(lco, cz.x, cz.y), fmax3(cz.x, cz.y, cz.z),
                   fmax3(cz.y, cz.z, cz.w), fmax3(cz.z, cz.w, rco)};
    float cs[4] = {c.x, c.y, c.z, c.w};
    bool pass[4];
    bool any = false;
#pragma unroll
    for (int k = 0; k < 4; ++k) {
        pass[k] = (ms[k] == cs[k]);
        any = any || pass[k];
    }
    if (!any) return;                 // ~86% of lanes: no gt fetch at all
    f4 g = __builtin_nontemporal_load((const f4*)gquad);
    float gs[4] = {g.x, g.y, g.z, g.w};
#pragma unroll
    for (int k = 0; k < 4; ++k) {
        if (pass[k] && gs[k] == -1.0f) {
            float e = __expf(cs[k]);                  // e^x
            float u = __builtin_amdgcn_rcpf(1.0f + e);
            float sc = e * u;                         // sigmoid(x)
            float wv = sc * sc;
            wsum += wv;
            loss += (-__logf(u)) * wv;                // softplus(x)
        }
    }
}

// One thread: fixed (x-quad, z-pair). Marches y0-1..y0+YR (YR+2 rows,
// clamped), emitting YR y-rows at BOTH z and z+1 from 4 planes z-1..z+2.
// Logit loads PLAIN (L1 reuse; NT regressed R13); gt loads conditional
// inside emit_row_cond. Boundary: index clamping duplicates an in-window
// value -> max unchanged. Emitted rows (1..YR) are interior -> no clamp in
// their gt offset.
template <int D, int LOG2D, int XQ, int YR>
__device__ __forceinline__ void neg_march2(
    const float* __restrict__ logits, const float* __restrict__ gt,
    int vol, int z, int y0, int xq, float& loss, float& wsum)
{
    const int x0 = xq << 2;
    const float* vb = logits + (vol << (3 * LOG2D));
    const int zm = z > 0 ? z - 1 : 0;              // z+1 <= D-1 by construction
    const int zq = z + 2 < D ? z + 2 : D - 1;
    const float* p0 = vb + (zm << (2 * LOG2D));
    const float* p1 = vb + (z << (2 * LOG2D));
    const float* p2 = vb + ((z + 1) << (2 * LOG2D));
    const float* p3 = vb + (zq << (2 * LOG2D));
    const float* g1 = gt + (vol << (3 * LOG2D)) + (z << (2 * LOG2D));
    const float* g2 = g1 + (1 << (2 * LOG2D));

    f4 za[3], zb[3];   // rings: z-folded col max for output z / z+1
    f4 ca[2], cb[2];   // rings: center raw quads (plane z / z+1)

#pragma unroll
    for (int s = 0; s < YR + 2; ++s) {
        int yy = y0 - 1 + s;
        yy = yy < 0 ? 0 : (yy > D - 1 ? D - 1 : yy);
        const int ro = (yy << LOG2D) + x0;
        f4 r0 = *(const f4*)(p0 + ro);
        f4 r1 = *(const f4*)(p1 + ro);
        f4 r2 = *(const f4*)(p2 + ro);
        f4 r3 = *(const f4*)(p3 + ro);
        za[s % 3] = fmax3v(r0, r1, r2);
        zb[s % 3] = fmax3v(r1, r2, r3);
        ca[s & 1] = r1;
        cb[s & 1] = r2;
        if (s >= 2) {
            // emitted row index = s-1 in [1,YR] -> yy_e = y0+s-2, unclamped
            const int roE = ((y0 + s - 2) << LOG2D) + x0;
            emit_row_cond<XQ>(za[0], za[1], za[2], ca[(s - 1) & 1], g1 + roE,
                              xq, loss, wsum);
            emit_row_cond<XQ>(zb[0], zb[1], zb[2], cb[(s - 1) & 1], g2 + roE,
                              xq, loss, wsum);
        }
    }
}

__global__ __launch_bounds__(256, 4) void fused_kernel(
    const float* __restrict__ la, const float* __restrict__ lb,
    const float* __restrict__ ga, const float* __restrict__ gb,
    const int* __restrict__ conn_a, const int* __restrict__ conn_b,
    const int* __restrict__ coord_a, const int* __restrict__ coord_b,
    float* __restrict__ ws, float* __restrict__ out)
{
    __shared__ float sred[8];
    __shared__ float w1s[256];
    __shared__ float tgf[256];
    const int bid = blockIdx.x;
    const int t = threadIdx.x;
    float loss = 0.0f, wsum = 0.0f;
    bool isNeg = false;

    if (bid == 0) {
        // pos block, FIRST scheduled: both levels CONCURRENT.
        // t<128: level a (coord index t), t>=128: level b (coord index t-128).
        const int lvl = t >> 7;
        const int u = t & 127;
        const float* logits = lvl ? lb : la;
        const int* conn = lvl ? conn_b : conn_a;
        const int* coord = lvl ? coord_b : coord_a;
        const int LOG2D = lvl ? 6 : 7;

        const int* c4 = coord + u * 4;
        int a = c4[0], zz = c4[1], yy = c4[2], xx = c4[3];
        bool valid = a > -1;
        int aa = valid ? a : 0, z2 = valid ? zz : 0,
            y2 = valid ? yy : 0, x2 = valid ? xx : 0;
        int b = u >> 6;
        int off = (((((b * 2 + aa) << LOG2D) + z2) << LOG2D) + y2 << LOG2D) + x2;
        float lp = logits[off];
        int tag = conn[off];
        float s = 1.0f / (1.0f + expf(lp));   // 1 - sigmoid(lp)
        float w1 = s * s;
        float vf = valid ? 1.0f : 0.0f;
        float sp = fmaxf(-lp, 0.0f) + log1pf(expf(-fabsf(lp)));  // softplus(-lp)
        float li = sp * w1 * vf;
        float ci = w1 * vf;
        w1s[t] = w1;
        tgf[t] = (float)(valid ? tag : -1);

        // per-wave sums (waves 0,1 = level a; waves 2,3 = level b)
        for (int o = 32; o; o >>= 1) {
            li += __shfl_down(li, o);
            ci += __shfl_down(ci, o);
        }
        if ((t & 63) == 0) { sred[t >> 6] = li; sred[4 + (t >> 6)] = ci; }
        __syncthreads();
        if (t == 0) {
            ws[WS_POS + 0] = sred[0] + sred[1];   // losspos_a
            ws[WS_POS + 1] = sred[4] + sred[5];   // cntpos_a
            ws[WS_POS + 2] = sred[2] + sred[3];   // losspos_b
            ws[WS_POS + 3] = sred[6] + sred[7];   // cntpos_b
        }
        // min-scan: 32 groups (lvl,bb,tg) x 8 lanes x 8 entries + shuffle fold
        {
            const int g = t >> 3;            // 0..31
            const int gl = g >> 4;           // level
            const int bb = (g >> 3) & 1;
            const int tg = g & 7;
            const float ftg = (float)tg;
            float mn = INFINITY;
#pragma unroll
            for (int k = 0; k < 8; ++k) {
                int j = gl * 128 + bb * 64 + (t & 7) * 8 + k;
                if (tgf[j] == ftg) mn = fminf(mn, w1s[j]);
            }
            mn = fminf(mn, __shfl_down(mn, 4));
            mn = fminf(mn, __shfl_down(mn, 2));
            mn = fminf(mn, __shfl_down(mn, 1));
            if ((t & 7) == 0)
                out[6 + gl * 16 + bb * 8 + tg] = isinf(mn) ? -1.0f : mn;
        }
    } else if (bid <= NBLK_A) {
        // level a: D=128, 256 threads: xq = t&31, z-pair = t>>5 (16 z x 8 y).
        // XCD spread: blocks with equal (nb&7) share an XCD -> one z-group.
        isNeg = true;
        const int nb = bid - 1;
        const int c = nb & 7;
        const int g = nb >> 3;         // 0..63
        const int yc = g & 15;         // y fastest
        const int vol = g >> 4;
        neg_march2<128, 7, 32, 8>(la, ga, vol, c * 16 + (t >> 5) * 2, yc * 8,
                                  t & 31, loss, wsum);
    } else {
        // level b: D=64, 128 active threads: xq = t&15, z-pair = t>>4 (0..7).
        isNeg = true;
        const int b2 = bid - 1 - NBLK_A;   // 0..255
        const int c = b2 & 7;
        const int vol = c >> 1;
        const int zg = (c & 1) * 2 + ((b2 >> 3) & 1);   // 0..3 (16 z each)
        const int yc = b2 >> 4;        // 0..15
        if (t < 128) {
            neg_march2<64, 6, 16, 4>(lb, gb, vol, zg * 16 + (t >> 4) * 2,
                                     yc * 4, t & 15, loss, wsum);
        }
    }

    if (isNeg) {
        for (int o = 32; o; o >>= 1) {
            loss += __shfl_down(loss, o);
            wsum += __shfl_down(wsum, o);
        }
        if ((t & 63) == 0) { sred[t >> 6] = loss; sred[4 + (t >> 6)] = wsum; }
        __syncthreads();
        if (t == 0) {
            f2 v;
            v.x = sred[0] + sred[1] + sred[2] + sred[3];
            v.y = sred[4] + sred[5] + sred[6] + sred[7];
            ((f2*)ws)[bid] = v;    // private 8B slot, zero contention
        }
    }
}

// Stream-ordered finalize: reduces the 768 block partials. No arrival
// counter, no fence — dispatch boundary provides ordering + visibility.
__global__ __launch_bounds__(256) void finalize_kernel(
    const float* __restrict__ ws, float* __restrict__ out)
{
    __shared__ float sred[32];
    const int t = threadIdx.x;
    float la = 0.0f, wa = 0.0f, lb = 0.0f, wb = 0.0f;
    for (int i = t; i < NBLK_NEG; i += 256) {
        f2 v = ((const f2*)ws)[1 + i];     // neg partials live at bid 1..768
        if (i < NBLK_A) { la += v.x; wa += v.y; }
        else            { lb += v.x; wb += v.y; }
    }
    for (int o = 32; o; o >>= 1) {
        la += __shfl_down(la, o);
        wa += __shfl_down(wa, o);
        lb += __shfl_down(lb, o);
        wb += __shfl_down(wb, o);
    }
    if ((t & 63) == 0) {
        int w = t >> 6;
        sred[w] = la; sred[8 + w] = wa; sred[16 + w] = lb; sred[24 + w] = wb;
    }
    __syncthreads();
    if (t == 0) {
        float s0 = 0, s1 = 0, s2 = 0, s3 = 0;
        for (int w = 0; w < 4; ++w) {
            s0 += sred[w]; s1 += sred[8 + w]; s2 += sred[16 + w]; s3 += sred[24 + w];
        }
        float lpa = ws[WS_POS + 0], cpa = ws[WS_POS + 1];
        float lpb = ws[WS_POS + 2], cpb = ws[WS_POS + 3];
        out[0] = lpa * 2.0f + lpb;   // cls_loss_pos (POS_FACTOR {2,1})
        out[1] = s0 * 2.0f + s2;     // cls_loss_neg (NEG_FACTOR {2,1})
        out[2] = cpa + cpb;          // count_pos
        out[3] = s1 + s3;            // count_neg
        out[4] = cpa * 2.0f + cpb;   // wsum_pos (anchor factor == 1)
        out[5] = s1 * 2.0f + s3;     // wsum_neg
    }
}

extern "C" void kernel_launch(void* const* d_in, const int* in_sizes, int n_in,
                              void* d_out, int out_size, void* d_ws, size_t ws_size,
                              hipStream_t stream) {
    const float* logits_a = (const float*)d_in[0];
    const float* logits_b = (const float*)d_in[1];
    const float* prob_a   = (const float*)d_in[2];
    const float* prob_b   = (const float*)d_in[3];
    const int*   conn_a   = (const int*)d_in[4];
    const int*   conn_b   = (const int*)d_in[5];
    const int*   coord_a  = (const int*)d_in[6];
    const int*   coord_b  = (const int*)d_in[7];
    float* out = (float*)d_out;
    float* ws  = (float*)d_ws;

    // No memset: every ws slot is unconditionally overwritten each iteration.
    fused_kernel<<<NBLK_TOTAL, 256, 0, stream>>>(
        logits_a, logits_b, prob_a, prob_b,
        conn_a, conn_b, coord_a, coord_b, ws, out);
    finalize_kernel<<<1, 256, 0, stream>>>(ws, out);
}

// Round 7
// 137.067 us; speedup vs baseline: 1.0589x; 1.0589x over previous
//
#include <hip/hip_runtime.h>
#include <math.h>

// Focal_loss2 — R20: REVERT to R18 (best measured: 137.7us).
// R19 post-mortem: conditional gt loads regressed +7.4us — (1) wave-level
// any-pass probability ~1 (64 lanes x 14%), so the branch never skips and
// line-granularity savings were small; (2) making gt fetch depend on the
// completed max test serialized a ~900cy chain per emit that R18's rolling
// stream had hidden. Lesson: never break load-issue overlap (R13, R19);
// wins came from removing serialized tails (R14 atomic tail, R18 pos tail).
// Config: z-paired rolling marcher, (256,4), 512 A-blocks (yc=8) + 256
// B-blocks (yc=4, 128 thr), pos block at bid 0 (first-scheduled, concurrent
// levels, parallel min-scan), logits PLAIN, gt NT, no global atomics,
// stream-ordered finalize. Remaining time: ~41us harness re-poison (81-85%
// HBM peak, not ours) + ~110us fixed overhead + fused near its cold-memory
// floor (TLP/balance/ILP/miss-count levers all measured null or negative).
//   neg: w = sigmoid(x)^2 * (gt==-1) * (x is 3x3x3 local max); loss += softplus(x)*w
//        local-max test in logit space (monotone sigmoid; validated R3-R18, absmax 0.0)
//   pos: 64 coords/batch/level gather; w1=(1-sigmoid)^2; per-(b,tag) min of w1
// ws layout (floats): f2[bid] = {loss,wsum} for neg bid in [1,769);
//   [1600..1603] = losspos_a,cntpos_a,losspos_b,cntpos_b
// out: [0]=cls_loss_pos [1]=cls_loss_neg [2]=count_pos [3]=count_neg
//      [4]=wsum_pos [5]=wsum_neg [6..37]=pred_prob_min[2][B=2][T=8]

#define NBLK_A 512    // 4 vol x 8 z-groups(16 z) x 16 y-chunks(8 y)
#define NBLK_B 256    // 4 vol x 4 z-groups(16 z) x 16 y-chunks(4 y)
#define NBLK_NEG (NBLK_A + NBLK_B)
#define NBLK_TOTAL (NBLK_NEG + 1)
#define WS_POS 1600   // clear of f2[0..768] = floats [0..1538)

using f4 = __attribute__((ext_vector_type(4))) float;
using f2 = __attribute__((ext_vector_type(2))) float;

__device__ __forceinline__ float fmax3(float a, float b, float c) {
    return fmaxf(a, fmaxf(b, c));
}

__device__ __forceinline__ f4 fmax3v(f4 a, f4 b, f4 c) {
    f4 r;
    r.x = fmax3(a.x, b.x, c.x); r.y = fmax3(a.y, b.y, c.y);
    r.z = fmax3(a.z, b.z, c.z); r.w = fmax3(a.w, b.w, c.w);
    return r;
}

// Emit one output quad. x-halo via wave shuffle (xq in low lane bits; group
// edges overridden by the clamp rule).
template <int XQ>
__device__ __forceinline__ void emit_row(
    const f4 zw0, const f4 zw1, const f4 zw2, const f4 c, const f4 g,
    int xq, float& loss, float& wsum)
{
    f4 cz = fmax3v(zw0, zw1, zw2);                    // y-fold
    float lco = __shfl_up(cz.w, 1);   if (xq == 0)      lco = cz.x;
    float rco = __shfl_down(cz.x, 1); if (xq == XQ - 1) rco = cz.w;
    float ms[4] = {fmax3(lco, cz.x, cz.y), fmax3(cz.x, cz.y, cz.z),
                   fmax3(cz.y, cz.z, cz.w), fmax3(cz.z, cz.w, rco)};
    float cs[4] = {c.x, c.y, c.z, c.w};
    float gs[4] = {g.x, g.y, g.z, g.w};
#pragma unroll
    for (int k = 0; k < 4; ++k) {
        if (gs[k] == -1.0f && ms[k] == cs[k]) {
            float e = __expf(cs[k]);                  // e^x
            float u = __builtin_amdgcn_rcpf(1.0f + e);
            float sc = e * u;                         // sigmoid(x)
            float wv = sc * sc;
            wsum += wv;
            loss += (-__logf(u)) * wv;                // softplus(x)
        }
    }
}

// One thread: fixed (x-quad, z-pair). Marches y0-1..y0+YR (YR+2 rows,
// clamped), emitting YR y-rows at BOTH z and z+1 from 4 planes z-1..z+2.
// Logit loads PLAIN, gt rows NT (issued inside the rolling stream so their
// latency hides under the logit pipeline). Boundary: index clamping
// duplicates an in-window value -> max unchanged.
template <int D, int LOG2D, int XQ, int YR>
__device__ __forceinline__ void neg_march2(
    const float* __restrict__ logits, const float* __restrict__ gt,
    int vol, int z, int y0, int xq, float& loss, float& wsum)
{
    const int x0 = xq << 2;
    const float* vb = logits + (vol << (3 * LOG2D));
    const int zm = z > 0 ? z - 1 : 0;              // z+1 <= D-1 by construction
    const int zq = z + 2 < D ? z + 2 : D - 1;
    const float* p0 = vb + (zm << (2 * LOG2D));
    const float* p1 = vb + (z << (2 * LOG2D));
    const float* p2 = vb + ((z + 1) << (2 * LOG2D));
    const float* p3 = vb + (zq << (2 * LOG2D));
    const float* g1 = gt + (vol << (3 * LOG2D)) + (z << (2 * LOG2D));
    const float* g2 = g1 + (1 << (2 * LOG2D));

    f4 za[3], zb[3];   // rings: z-folded col max for output z / z+1
    f4 ca[2], cb[2];   // rings: center raw quads (plane z / z+1)
    f4 ga[2], gb[2];   // rings: gt quads

#pragma unroll
    for (int s = 0; s < YR + 2; ++s) {
        int yy = y0 - 1 + s;
        yy = yy < 0 ? 0 : (yy > D - 1 ? D - 1 : yy);
        const int ro = (yy << LOG2D) + x0;
        f4 r0 = *(const f4*)(p0 + ro);
        f4 r1 = *(const f4*)(p1 + ro);
        f4 r2 = *(const f4*)(p2 + ro);
        f4 r3 = *(const f4*)(p3 + ro);
        if (s >= 1 && s <= YR) {      // gt rows: single-use stream
            ga[s & 1] = __builtin_nontemporal_load((const f4*)(g1 + ro));
            gb[s & 1] = __builtin_nontemporal_load((const f4*)(g2 + ro));
        }
        za[s % 3] = fmax3v(r0, r1, r2);
        zb[s % 3] = fmax3v(r1, r2, r3);
        ca[s & 1] = r1;
        cb[s & 1] = r2;
        if (s >= 2) {
            emit_row<XQ>(za[0], za[1], za[2], ca[(s - 1) & 1], ga[(s - 1) & 1],
                         xq, loss, wsum);
            emit_row<XQ>(zb[0], zb[1], zb[2], cb[(s - 1) & 1], gb[(s - 1) & 1],
                         xq, loss, wsum);
        }
    }
}

__global__ __launch_bounds__(256, 4) void fused_kernel(
    const float* __restrict__ la, const float* __restrict__ lb,
    const float* __restrict__ ga, const float* __restrict__ gb,
    const int* __restrict__ conn_a, const int* __restrict__ conn_b,
    const int* __restrict__ coord_a, const int* __restrict__ coord_b,
    float* __restrict__ ws, float* __restrict__ out)
{
    __shared__ float sred[8];
    __shared__ float w1s[256];
    __shared__ float tgf[256];
    const int bid = blockIdx.x;
    const int t = threadIdx.x;
    float loss = 0.0f, wsum = 0.0f;
    bool isNeg = false;

    if (bid == 0) {
        // pos block, FIRST scheduled: both levels CONCURRENT.
        // t<128: level a (coord index t), t>=128: level b (coord index t-128).
        const int lvl = t >> 7;
        const int u = t & 127;
        const float* logits = lvl ? lb : la;
        const int* conn = lvl ? conn_b : conn_a;
        const int* coord = lvl ? coord_b : coord_a;
        const int LOG2D = lvl ? 6 : 7;

        const int* c4 = coord + u * 4;
        int a = c4[0], zz = c4[1], yy = c4[2], xx = c4[3];
        bool valid = a > -1;
        int aa = valid ? a : 0, z2 = valid ? zz : 0,
            y2 = valid ? yy : 0, x2 = valid ? xx : 0;
        int b = u >> 6;
        int off = (((((b * 2 + aa) << LOG2D) + z2) << LOG2D) + y2 << LOG2D) + x2;
        float lp = logits[off];
        int tag = conn[off];
        float s = 1.0f / (1.0f + expf(lp));   // 1 - sigmoid(lp)
        float w1 = s * s;
        float vf = valid ? 1.0f : 0.0f;
        float sp = fmaxf(-lp, 0.0f) + log1pf(expf(-fabsf(lp)));  // softplus(-lp)
        float li = sp * w1 * vf;
        float ci = w1 * vf;
        w1s[t] = w1;
        tgf[t] = (float)(valid ? tag : -1);

        // per-wave sums (waves 0,1 = level a; waves 2,3 = level b)
        for (int o = 32; o; o >>= 1) {
            li += __shfl_down(li, o);
            ci += __shfl_down(ci, o);
        }
        if ((t & 63) == 0) { sred[t >> 6] = li; sred[4 + (t >> 6)] = ci; }
        __syncthreads();
        if (t == 0) {
            ws[WS_POS + 0] = sred[0] + sred[1];   // losspos_a
            ws[WS_POS + 1] = sred[4] + sred[5];   // cntpos_a
            ws[WS_POS + 2] = sred[2] + sred[3];   // losspos_b
            ws[WS_POS + 3] = sred[6] + sred[7];   // cntpos_b
        }
        // min-scan: 32 groups (lvl,bb,tg) x 8 lanes x 8 entries + shuffle fold
        {
            const int g = t >> 3;            // 0..31
            const int gl = g >> 4;           // level
            const int bb = (g >> 3) & 1;
            const int tg = g & 7;
            const float ftg = (float)tg;
            float mn = INFINITY;
#pragma unroll
            for (int k = 0; k < 8; ++k) {
                int j = gl * 128 + bb * 64 + (t & 7) * 8 + k;
                if (tgf[j] == ftg) mn = fminf(mn, w1s[j]);
            }
            mn = fminf(mn, __shfl_down(mn, 4));
            mn = fminf(mn, __shfl_down(mn, 2));
            mn = fminf(mn, __shfl_down(mn, 1));
            if ((t & 7) == 0)
                out[6 + gl * 16 + bb * 8 + tg] = isinf(mn) ? -1.0f : mn;
        }
    } else if (bid <= NBLK_A) {
        // level a: D=128, 256 threads: xq = t&31, z-pair = t>>5 (16 z x 8 y).
        // XCD spread: blocks with equal (nb&7) share an XCD -> one z-group.
        isNeg = true;
        const int nb = bid - 1;
        const int c = nb & 7;
        const int g = nb >> 3;         // 0..63
        const int yc = g & 15;         // y fastest
        const int vol = g >> 4;
        neg_march2<128, 7, 32, 8>(la, ga, vol, c * 16 + (t >> 5) * 2, yc * 8,
                                  t & 31, loss, wsum);
    } else {
        // level b: D=64, 128 active threads: xq = t&15, z-pair = t>>4 (0..7).
        isNeg = true;
        const int b2 = bid - 1 - NBLK_A;   // 0..255
        const int c = b2 & 7;
        const int vol = c >> 1;
        const int zg = (c & 1) * 2 + ((b2 >> 3) & 1);   // 0..3 (16 z each)
        const int yc = b2 >> 4;        // 0..15
        if (t < 128) {
            neg_march2<64, 6, 16, 4>(lb, gb, vol, zg * 16 + (t >> 4) * 2,
                                     yc * 4, t & 15, loss, wsum);
        }
    }

    if (isNeg) {
        for (int o = 32; o; o >>= 1) {
            loss += __shfl_down(loss, o);
            wsum += __shfl_down(wsum, o);
        }
        if ((t & 63) == 0) { sred[t >> 6] = loss; sred[4 + (t >> 6)] = wsum; }
        __syncthreads();
        if (t == 0) {
            f2 v;
            v.x = sred[0] + sred[1] + sred[2] + sred[3];
            v.y = sred[4] + sred[5] + sred[6] + sred[7];
            ((f2*)ws)[bid] = v;    // private 8B slot, zero contention
        }
    }
}

// Stream-ordered finalize: reduces the 768 block partials. No arrival
// counter, no fence — dispatch boundary provides ordering + visibility.
__global__ __launch_bounds__(256) void finalize_kernel(
    const float* __restrict__ ws, float* __restrict__ out)
{
    __shared__ float sred[32];
    const int t = threadIdx.x;
    float la = 0.0f, wa = 0.0f, lb = 0.0f, wb = 0.0f;
    for (int i = t; i < NBLK_NEG; i += 256) {
        f2 v = ((const f2*)ws)[1 + i];     // neg partials live at bid 1..768
        if (i < NBLK_A) { la += v.x; wa += v.y; }
        else            { lb += v.x; wb += v.y; }
    }
    for (int o = 32; o; o >>= 1) {
        la += __shfl_down(la, o);
        wa += __shfl_down(wa, o);
        lb += __shfl_down(lb, o);
        wb += __shfl_down(wb, o);
    }
    if ((t & 63) == 0) {
        int w = t >> 6;
        sred[w] = la; sred[8 + w] = wa; sred[16 + w] = lb; sred[24 + w] = wb;
    }
    __syncthreads();
    if (t == 0) {
        float s0 = 0, s1 = 0, s2 = 0, s3 = 0;
        for (int w = 0; w < 4; ++w) {
            s0 += sred[w]; s1 += sred[8 + w]; s2 += sred[16 + w]; s3 += sred[24 + w];
        }
        float lpa = ws[WS_POS + 0], cpa = ws[WS_POS + 1];
        float lpb = ws[WS_POS + 2], cpb = ws[WS_POS + 3];
        out[0] = lpa * 2.0f + lpb;   // cls_loss_pos (POS_FACTOR {2,1})
        out[1] = s0 * 2.0f + s2;     // cls_loss_neg (NEG_FACTOR {2,1})
        out[2] = cpa + cpb;          // count_pos
        out[3] = s1 + s3;            // count_neg
        out[4] = cpa * 2.0f + cpb;   // wsum_pos (anchor factor == 1)
        out[5] = s1 * 2.0f + s3;     // wsum_neg
    }
}

extern "C" void kernel_launch(void* const* d_in, const int* in_sizes, int n_in,
                              void* d_out, int out_size, void* d_ws, size_t ws_size,
                              hipStream_t stream) {
    const float* logits_a = (const float*)d_in[0];
    const float* logits_b = (const float*)d_in[1];
    const float* prob_a   = (const float*)d_in[2];
    const float* prob_b   = (const float*)d_in[3];
    const int*   conn_a   = (const int*)d_in[4];
    const int*   conn_b   = (const int*)d_in[5];
    const int*   coord_a  = (const int*)d_in[6];
    const int*   coord_b  = (const int*)d_in[7];
    float* out = (float*)d_out;
    float* ws  = (float*)d_ws;

    // No memset: every ws slot is unconditionally overwritten each iteration.
    fused_kernel<<<NBLK_TOTAL, 256, 0, stream>>>(
        logits_a, logits_b, prob_a, prob_b,
        conn_a, conn_b, coord_a, coord_b, ws, out);
    finalize_kernel<<<1, 256, 0, stream>>>(ws, out);
}